// Round 1
// 3940.581 us; speedup vs baseline: 1.4559x; 1.4559x over previous
//
#include <hip/hip_runtime.h>
#include <hip/hip_bf16.h>

// Problem constants: B=32, D=128, T=2250, Q=32, K=1024
#define B_ 32
#define D_ 128
#define T_ 2250
#define Q_ 32
#define K_ 1024
#define N_ (B_ * T_)      // 72000 = 64 * 1125
#define TAU 0.25f
#define COFF 640.0f       // score offset: v = 2 r.e + (COFF - ||e||^2), positive for this data

typedef _Float16 half8 __attribute__((ext_vector_type(8)));
typedef float f32x4 __attribute__((ext_vector_type(4)));

__device__ __forceinline__ unsigned int pack2h(float a, float b) {
    _Float16 ha = (_Float16)a, hb = (_Float16)b;
    unsigned short ua = *(unsigned short*)&ha, ub = *(unsigned short*)&hb;
    return (unsigned int)ua | ((unsigned int)ub << 16);
}

// ---------------------------------------------------------------------------
// Transpose embeddings [B, D, T] -> R64 [N,128] fp64 (n = b*T + t)
// ---------------------------------------------------------------------------
__global__ void transpose_kernel(const float* __restrict__ emb,
                                 double* __restrict__ R64)
{
    __shared__ float tile[32][33];
    const int b  = blockIdx.z;
    const int t0 = blockIdx.x * 32;
    const int d0 = blockIdx.y * 32;

    for (int i = threadIdx.y; i < 32; i += 8) {
        int t = t0 + threadIdx.x;
        int d = d0 + i;
        tile[i][threadIdx.x] = (t < T_) ? emb[((size_t)b * D_ + d) * T_ + t] : 0.0f;
    }
    __syncthreads();
    for (int i = threadIdx.y; i < 32; i += 8) {
        int t = t0 + i;
        if (t < T_) {
            size_t o = ((size_t)b * T_ + t) * D_ + d0 + threadIdx.x;
            R64[o] = (double)tile[threadIdx.x][i];
        }
    }
}

// ---------------------------------------------------------------------------
// Codebook conversion: E16 = fp16(2*e)   [Q*K*D]
// ---------------------------------------------------------------------------
__global__ void cvt_cb_kernel(const float* __restrict__ cbs,
                              _Float16* __restrict__ E16)
{
    int i = blockIdx.x * 256 + threadIdx.x;   // Q*K*D threads exactly
    E16[i] = (_Float16)(2.0f * cbs[i]);
}

// ---------------------------------------------------------------------------
// Per-code norms: cNorm = COFF - ||e||^2 (fp32), normD = ||e||^2 (fp64)
// ---------------------------------------------------------------------------
__global__ __launch_bounds__(64) void norms_kernel(const float* __restrict__ codebooks,
                                                   float* __restrict__ cNorm,
                                                   double* __restrict__ normD)
{
    const int code = blockIdx.x;            // 0 .. Q*K-1
    const float* e = codebooks + (size_t)code * D_;
    const int lane = threadIdx.x;
    float f0 = e[lane];
    float f1 = e[lane + 64];
    double acc = (double)f0 * (double)f0 + (double)f1 * (double)f1;
    #pragma unroll
    for (int off = 32; off > 0; off >>= 1) acc += __shfl_down(acc, off);
    if (lane == 0) {
        normD[code] = acc;
        cNorm[code] = COFF - (float)acc;
    }
}

// ---------------------------------------------------------------------------
// fp16 single-pass MFMA fast pass with fused fp64 residual update.
// Block = 64 points x ALL 1024 codes; 256 threads = 4 waves.
// Stripe = 128 codes; wave w owns codes [w*32, w*32+32) of each stripe.
// A = fp16(residual), 16 KB LDS, XOR-swizzled. B = fp16(2e) from L2,
// double-buffered across c-groups and stripe boundaries.
// Error model: score err ~<=0.1 worst << TAU; flagged near-ties resolved
// by the fp64 rescore (correctness machinery proven R2-R8).
// ---------------------------------------------------------------------------
__global__ __launch_bounds__(256) void layer_fast(
    double* __restrict__ R64,                 // [N,128] read/modify/write
    const int* __restrict__ prevIdx,          // [N] prev layer's indices (null for q==0)
    const float* __restrict__ cbPrev,         // [K,128] prev layer's fp32 codebook
    const _Float16* __restrict__ E16,         // [K,128] fp16(2e), layer slice
    const float* __restrict__ cNorm,          // [K] COFF - ||e||^2
    int* __restrict__ outIdx,
    int* __restrict__ flagList,
    int* __restrict__ flagCount)
{
    __shared__ __align__(16) char lds[16384];  // A fp16 [64 rows x 256 B]

    const int tid  = threadIdx.x;
    const int lane = tid & 63;
    const int w    = tid >> 6;
    const int mBase = blockIdx.x * 64;        // grid 1125 -> exact, no guards

    // ---- Prologue: fused fp64 residual update + fp16 convert into LDS ----
    {
        double2* R64v = (double2*)R64;
        const float2* cbv = (const float2*)cbPrev;
        const int d = lane * 2;                   // dims d, d+1
        const int gsh = ((d >> 3) << 4);          // granule*16
        const int bofs = (d & 7) * 2;             // byte offset within granule
        #pragma unroll 8
        for (int k = 0; k < 16; ++k) {
            const int row = k * 4 + w;            // wave-uniform local row
            const int grow = mBase + row;
            double2 rv = R64v[(size_t)grow * 64 + lane];
            double rx = rv.x, ry = rv.y;
            if (prevIdx) {
                int code = prevIdx[grow];                    // wave-uniform
                float2 ev = cbv[(size_t)code * 64 + lane];   // coalesced row
                rx -= (double)ev.x;
                ry -= (double)ev.y;
                double2 nv; nv.x = rx; nv.y = ry;
                R64v[(size_t)grow * 64 + lane] = nv;
            }
            const int lofs = row * 256 + (gsh ^ ((row & 15) << 4)) + bofs;
            *(unsigned int*)(lds + lofs) = pack2h((float)rx, (float)ry);
        }
    }
    __syncthreads();

    const int l15  = lane & 15;
    const int quad = lane >> 4;

    // A fragment addressing (XOR-swizzled granules; frag rows have row&15==l15)
    const int aRowByte = l15 * 256;               // + i*4096 for i-th 16-row group
    int gofs[4];
    #pragma unroll
    for (int c = 0; c < 4; ++c) gofs[c] = (((c * 4 + quad) ^ l15) << 4);

    // B global lane base: code row = st*128 + w*32 + j*16 + l15 (256 B rows)
    const size_t bLane = ((size_t)(w * 32 + l15)) * 256 + (size_t)quad * 16;
    const char* BB = (const char*)E16 + bLane;

    // packed running top-2 for this lane's 16 points (s = i*4 + r)
    unsigned int b1[16], b2[16];
    #pragma unroll
    for (int s = 0; s < 16; ++s) { b1[s] = 0u; b2[s] = 0u; }

    // prefetch (st=0, c=0) B fragments
    half8 bc[2];
    #pragma unroll
    for (int j = 0; j < 2; ++j) bc[j] = *(const half8*)(BB + j * 4096);

    #pragma unroll 1
    for (int st = 0; st < 8; ++st) {
        f32x4 acc[4][2];
        #pragma unroll
        for (int i = 0; i < 4; ++i)
            #pragma unroll
            for (int j = 0; j < 2; ++j) acc[i][j] = (f32x4){0.f, 0.f, 0.f, 0.f};

        #pragma unroll
        for (int c = 0; c < 4; ++c) {
            // prefetch next c-group (crossing stripe boundaries)
            half8 bn[2];
            const bool hn = (c < 3) || (st < 7);
            if (hn) {
                size_t noff = (c < 3) ? ((size_t)st * 32768 + (size_t)(c + 1) * 64)
                                      : ((size_t)(st + 1) * 32768);
                #pragma unroll
                for (int j = 0; j < 2; ++j) bn[j] = *(const half8*)(BB + noff + j * 4096);
            }
            half8 ah[4];
            #pragma unroll
            for (int i = 0; i < 4; ++i)
                ah[i] = *(const half8*)(lds + aRowByte + i * 4096 + gofs[c]);
            #pragma unroll
            for (int i = 0; i < 4; ++i)
                #pragma unroll
                for (int j = 0; j < 2; ++j)
                    acc[i][j] = __builtin_amdgcn_mfma_f32_16x16x32_f16(ah[i], bc[j], acc[i][j], 0, 0, 0);
            if (hn) {
                bc[0] = bn[0]; bc[1] = bn[1];
            }
        }

        // epilogue: pack scores, update packed top-2
        #pragma unroll
        for (int j = 0; j < 2; ++j) {
            const int code = st * 128 + w * 32 + j * 16 + l15;
            const float cn = cNorm[code];
            const unsigned int invc = 1023u - (unsigned int)code;
            #pragma unroll
            for (int i = 0; i < 4; ++i)
                #pragma unroll
                for (int r = 0; r < 4; ++r) {
                    float v = fmaxf(acc[i][j][r] + cn, 1.0f);    // positive -> uint-ordered
                    unsigned int p = (__float_as_uint(v) & 0xFFFFFC00u) | invc;
                    const int s = i * 4 + r;
                    unsigned int t  = (b1[s] > p) ? b1[s] : p;
                    unsigned int mn = (b1[s] < p) ? b1[s] : p;
                    b2[s] = (b2[s] > mn) ? b2[s] : mn;
                    b1[s] = t;
                }
        }
    }

    // ---- cross-l15 merge (butterfly over low 4 lane bits), packed ----
    #pragma unroll
    for (int m = 1; m < 16; m <<= 1) {
        #pragma unroll
        for (int s = 0; s < 16; ++s) {
            unsigned int o1 = (unsigned int)__shfl_xor((int)b1[s], m);
            unsigned int o2 = (unsigned int)__shfl_xor((int)b2[s], m);
            unsigned int n1 = (b1[s] > o1) ? b1[s] : o1;
            unsigned int mn = (b1[s] < o1) ? b1[s] : o1;
            unsigned int mx2 = (b2[s] > o2) ? b2[s] : o2;
            b2[s] = (mn > mx2) ? mn : mx2;
            b1[s] = n1;
        }
    }

    // ---- cross-wave merge (4 waves = 4 code bands) via LDS ----
    __syncthreads();                     // done with A region
    unsigned int* m1 = (unsigned int*)lds;            // [4][64]
    unsigned int* m2 = (unsigned int*)(lds + 1024);
    if (l15 == 0) {
        #pragma unroll
        for (int i = 0; i < 4; ++i)
            #pragma unroll
            for (int r = 0; r < 4; ++r) {
                int p = i * 16 + quad * 4 + r;
                m1[w * 64 + p] = b1[i * 4 + r];
                m2[w * 64 + p] = b2[i * 4 + r];
            }
    }
    __syncthreads();
    if (tid < 64) {
        unsigned int f1 = m1[tid], f2 = m2[tid];
        #pragma unroll
        for (int ww = 1; ww < 4; ++ww) {
            unsigned int c1 = m1[ww * 64 + tid], c2 = m2[ww * 64 + tid];
            unsigned int mn  = (f1 < c1) ? f1 : c1;
            f1               = (f1 > c1) ? f1 : c1;
            unsigned int mx2 = (f2 > c2) ? f2 : c2;
            f2 = (mn > mx2) ? mn : mx2;
        }
        const int n = mBase + tid;
        outIdx[n] = 1023 - (int)(f1 & 0x3FFu);
        float g1 = __uint_as_float(f1 & 0xFFFFFC00u);
        float g2 = __uint_as_float(f2 & 0xFFFFFC00u);
        if (g1 - g2 < TAU) {
            int pos = atomicAdd(flagCount, 1);
            flagList[pos] = n;
        }
    }
}

// ---------------------------------------------------------------------------
// fp64 rescore of flagged points, batched: 8 points per 256-thread block.
// Residuals staged in LDS (broadcast reads); each thread owns 4 consecutive
// codes -> acc[4][8] = 32 independent fp64 FMA chains (issue-bound, not
// latency-bound); float4 codebook loads with 8x reuse per load.
// Scoring math identical to the proven version: s = 2*(r.c) - ||c||^2 in
// fp64, argmax with lowest-k tie-break.
// ---------------------------------------------------------------------------
#define RPTS 8
__global__ __launch_bounds__(256) void layer_rescore(
    const double* __restrict__ R64,
    const float* __restrict__ cb,
    const double* __restrict__ normD,
    const int* __restrict__ flagList,
    const int* __restrict__ flagCount,
    int* __restrict__ outIdx)
{
    __shared__ __align__(16) double rs[RPTS][D_];   // 8 KB
    __shared__ double redS[4][RPTS];
    __shared__ int    redK[4][RPTS];

    const int cnt = *flagCount;
    if (cnt == 0) return;
    const int tid  = threadIdx.x;
    const int lane = tid & 63;
    const int w    = tid >> 6;
    const int nGroups = (cnt + RPTS - 1) / RPTS;

    for (int g = blockIdx.x; g < nGroups; g += gridDim.x) {
        const int base = g * RPTS;
        const int rem  = cnt - base;
        const int npts = (rem < RPTS) ? rem : RPTS;

        __syncthreads();   // protect rs/redS from previous iteration readers
        for (int i = tid; i < RPTS * D_; i += 256) {
            const int p = i >> 7, j = i & (D_ - 1);
            rs[p][j] = (p < npts) ? R64[(size_t)flagList[base + p] * D_ + j] : 0.0;
        }
        __syncthreads();

        const float* __restrict__ c0 = cb + (size_t)tid * 4 * D_;
        double acc[4][RPTS];
        #pragma unroll
        for (int cc = 0; cc < 4; ++cc)
            #pragma unroll
            for (int p = 0; p < RPTS; ++p) acc[cc][p] = 0.0;

        #pragma unroll 2
        for (int j = 0; j < D_; j += 4) {
            f32x4 cv[4];
            #pragma unroll
            for (int cc = 0; cc < 4; ++cc)
                cv[cc] = *(const f32x4*)(c0 + cc * D_ + j);
            #pragma unroll
            for (int p = 0; p < RPTS; ++p) {
                const double r0 = rs[p][j],     r1 = rs[p][j + 1];
                const double r2 = rs[p][j + 2], r3 = rs[p][j + 3];
                #pragma unroll
                for (int cc = 0; cc < 4; ++cc) {
                    acc[cc][p] = fma((double)cv[cc][0], r0, acc[cc][p]);
                    acc[cc][p] = fma((double)cv[cc][1], r1, acc[cc][p]);
                    acc[cc][p] = fma((double)cv[cc][2], r2, acc[cc][p]);
                    acc[cc][p] = fma((double)cv[cc][3], r3, acc[cc][p]);
                }
            }
        }

        // per-point argmax: thread-local (4 codes) -> wave butterfly -> block
        #pragma unroll
        for (int p = 0; p < RPTS; ++p) {
            double bs = -1.0e300;
            int bk = K_;
            #pragma unroll
            for (int cc = 0; cc < 4; ++cc) {
                const int k = tid * 4 + cc;
                double s = 2.0 * acc[cc][p] - normD[k];
                if (s > bs) { bs = s; bk = k; }   // ascending cc: lowest k wins
            }
            #pragma unroll
            for (int m = 1; m < 64; m <<= 1) {
                double os = __shfl_xor(bs, m);
                int    ok = __shfl_xor(bk, m);
                if (os > bs || (os == bs && ok < bk)) { bs = os; bk = ok; }
            }
            if (lane == 0) { redS[w][p] = bs; redK[w][p] = bk; }
        }
        __syncthreads();
        if (tid < npts) {
            double bs = redS[0][tid];
            int    bk = redK[0][tid];
            #pragma unroll
            for (int ww = 1; ww < 4; ++ww) {
                double s = redS[ww][tid];
                int    k = redK[ww][tid];
                if (s > bs || (s == bs && k < bk)) { bs = s; bk = k; }
            }
            outIdx[flagList[base + tid]] = bk;
        }
    }
}

// ---------------------------------------------------------------------------
extern "C" void kernel_launch(void* const* d_in, const int* in_sizes, int n_in,
                              void* d_out, int out_size, void* d_ws, size_t ws_size,
                              hipStream_t stream)
{
    const float* emb       = (const float*)d_in[0];   // [B, D, T] fp32
    const float* codebooks = (const float*)d_in[1];   // [Q, K, D] fp32
    int* outIdx = (int*)d_out;                        // [Q, B, T] int32

    char* ws = (char*)d_ws;
    double* R64  = (double*)ws;                        size_t off = (size_t)N_ * D_ * 8;
    double* normD = (double*)(ws + off);               off += (size_t)Q_ * K_ * 8;
    _Float16* E16 = (_Float16*)(ws + off);             off += (size_t)Q_ * K_ * D_ * 2;
    float* cNorm    = (float*)(ws + off);              off += (size_t)Q_ * K_ * 4;
    int*   flagList = (int*)(ws + off);                off += (size_t)N_ * 4;
    int*   counters = (int*)(ws + off);                off += (size_t)Q_ * 4;

    hipMemsetAsync(counters, 0, Q_ * 4, stream);

    dim3 tb(32, 8, 1);
    dim3 tg((T_ + 31) / 32, D_ / 32, B_);
    transpose_kernel<<<tg, tb, 0, stream>>>(emb, R64);
    cvt_cb_kernel<<<(Q_ * K_ * D_) / 256, 256, 0, stream>>>(codebooks, E16);
    norms_kernel<<<Q_ * K_, 64, 0, stream>>>(codebooks, cNorm, normD);

    for (int q = 0; q < Q_; ++q) {
        int* oq = outIdx + (size_t)q * N_;
        const int* prevIdx = (q > 0) ? (outIdx + (size_t)(q - 1) * N_) : nullptr;
        const float* cbPrev = codebooks + (size_t)(q > 0 ? q - 1 : 0) * K_ * D_;
        layer_fast<<<N_ / 64, 256, 0, stream>>>(
            R64, prevIdx, cbPrev,
            E16 + (size_t)q * K_ * D_,
            cNorm + (size_t)q * K_, oq, flagList, counters + q);
        layer_rescore<<<1024, 256, 0, stream>>>(
            R64, codebooks + (size_t)q * K_ * D_, normD + (size_t)q * K_,
            flagList, counters + q, oq);
    }
}